// Round 1
// baseline (3124.034 us; speedup 1.0000x reference)
//
#include <hip/hip_runtime.h>
#include <math.h>

#define NN 50000
#define DD 128
#define HH 128
#define L1 64
#define L2 32
#define OO 10

// ---------------- K1: support[row][h] = sum_d x[row][d] * W[d][h] ----------------
// block = 256 threads, 8 rows/block. x rows staged in LDS; W streamed from L1/L2.
__global__ __launch_bounds__(256) void k_support(
    const float* __restrict__ x, const float* __restrict__ W,
    float* __restrict__ support, int rows)
{
    __shared__ float xs[8][DD];
    const int tid = threadIdx.x;
    const int row0 = blockIdx.x * 8;
    {
        int r = tid >> 5;
        int c4 = (tid & 31) << 2;
        int row = row0 + r;
        float4 v = make_float4(0.f, 0.f, 0.f, 0.f);
        if (row < rows) v = *(const float4*)(x + (size_t)row * DD + c4);
        *(float4*)(&xs[r][c4]) = v;
    }
    __syncthreads();

    const int ln = tid >> 5;        // local row 0..7
    const int fg = tid & 31;        // feature group (4 feats)
    const int row = row0 + ln;
    if (row >= rows) return;

    float4 acc = make_float4(0.f, 0.f, 0.f, 0.f);
    const float* wp = W + fg * 4;
    #pragma unroll 4
    for (int k = 0; k < DD; ++k) {
        float xv = xs[ln][k];
        float4 w = *(const float4*)(wp + (size_t)k * HH);
        acc.x += xv * w.x; acc.y += xv * w.y;
        acc.z += xv * w.z; acc.w += xv * w.w;
    }
    *(float4*)(support + (size_t)row * HH + fg * 4) = acc;
}

// ---------------- K2: agg[b][dst] += support[b][src] over edges ----------------
// 32 threads per edge (4 floats each), both batches inside to reuse index loads.
__global__ __launch_bounds__(256) void k_scatter(
    const int* __restrict__ ei, const float* __restrict__ support,
    float* __restrict__ agg, int E, int B)
{
    const int tid = threadIdx.x;
    const int eg = tid >> 5;
    const int t4 = (tid & 31) << 2;
    const int e = blockIdx.x * 8 + eg;
    if (e >= E) return;
    const int src = ei[e];
    const int dst = ei[E + e];
    for (int b = 0; b < B; ++b) {
        const float4 v = *(const float4*)(support + ((size_t)b * NN + src) * HH + t4);
        float* ap = agg + ((size_t)b * NN + dst) * HH + t4;
        unsafeAtomicAdd(ap + 0, v.x);
        unsafeAtomicAdd(ap + 1, v.y);
        unsafeAtomicAdd(ap + 2, v.z);
        unsafeAtomicAdd(ap + 3, v.w);
    }
}

// ---------------- K3: h=gelu(agg+b); MLP 128->64->32->10; mean over nodes ------
// block = 256 = 4 node-rows x 64 lanes. All weights staged in LDS (~44 KB).
__global__ __launch_bounds__(256) void k_mlp(
    const float* __restrict__ agg,
    const float* __restrict__ b0v, const float* __restrict__ W1, const float* __restrict__ b1v,
    const float* __restrict__ W2, const float* __restrict__ b2v,
    const float* __restrict__ W3, const float* __restrict__ b3v,
    float* __restrict__ out, int rows, int B)
{
    __shared__ float w1s[HH * L1];   // 32 KB
    __shared__ float w2s[L1 * L2];   // 8 KB
    __shared__ float w3s[L2 * OO];   // 1.25 KB
    __shared__ float b0s[HH], b1s[L1], b2s[L2], b3s[OO];
    __shared__ float hs[4][HH];
    __shared__ float h1s[4][L1];
    __shared__ float h2s[4][L2];
    __shared__ float oacc[2 * OO];

    const int tid = threadIdx.x;
    for (int i = tid; i < HH * L1; i += 256) w1s[i] = W1[i];
    for (int i = tid; i < L1 * L2; i += 256) w2s[i] = W2[i];
    for (int i = tid; i < L2 * OO; i += 256) w3s[i] = W3[i];
    if (tid < HH) b0s[tid] = b0v[tid];
    if (tid < L1) b1s[tid] = b1v[tid];
    if (tid < L2) b2s[tid] = b2v[tid];
    if (tid < OO) b3s[tid] = b3v[tid];
    if (tid < 2 * OO) oacc[tid] = 0.f;
    __syncthreads();

    const int ln = tid >> 6;     // node in group 0..3
    const int lane = tid & 63;

    const int ngroups = (rows + 3) >> 2;
    for (int g = blockIdx.x; g < ngroups; g += gridDim.x) {
        const int row = g * 4 + ln;
        const bool valid = row < rows;
        if (valid) {
            float a0 = agg[(size_t)row * HH + lane] + b0s[lane];
            float a1 = agg[(size_t)row * HH + 64 + lane] + b0s[64 + lane];
            hs[ln][lane]      = 0.5f * a0 * (1.f + erff(a0 * 0.70710678118654752f));
            hs[ln][64 + lane] = 0.5f * a1 * (1.f + erff(a1 * 0.70710678118654752f));
        }
        __syncthreads();
        if (valid) {
            float acc = b1s[lane];
            #pragma unroll 8
            for (int j = 0; j < HH; ++j) acc += hs[ln][j] * w1s[j * L1 + lane];
            h1s[ln][lane] = fmaxf(acc, 0.f);
        }
        __syncthreads();
        if (valid && lane < L2) {
            float acc = b2s[lane];
            #pragma unroll 8
            for (int j = 0; j < L1; ++j) acc += h1s[ln][j] * w2s[j * L2 + lane];
            h2s[ln][lane] = fmaxf(acc, 0.f);
        }
        __syncthreads();
        if (valid && lane < OO) {
            float acc = b3s[lane];
            #pragma unroll
            for (int j = 0; j < L2; ++j) acc += h2s[ln][j] * w3s[j * OO + lane];
            const int batch = row / NN;
            atomicAdd(&oacc[batch * OO + lane], acc);
        }
        __syncthreads();
    }
    if (tid < B * OO) {
        atomicAdd(out + tid, oacc[tid] * (1.0f / (float)NN));
    }
}

extern "C" void kernel_launch(void* const* d_in, const int* in_sizes, int n_in,
                              void* d_out, int out_size, void* d_ws, size_t ws_size,
                              hipStream_t stream) {
    const float* x  = (const float*)d_in[0];
    const int*   ei = (const int*)d_in[1];
    const float* W  = (const float*)d_in[2];
    const float* b0 = (const float*)d_in[3];
    const float* W1 = (const float*)d_in[4];
    const float* b1 = (const float*)d_in[5];
    const float* W2 = (const float*)d_in[6];
    const float* b2 = (const float*)d_in[7];
    const float* W3 = (const float*)d_in[8];
    const float* b3 = (const float*)d_in[9];
    float* out = (float*)d_out;

    const int B = in_sizes[0] / (NN * DD);   // 2
    const int E = in_sizes[1] / 2;           // 800000
    const int rows = B * NN;                 // 100000

    float* support = (float*)d_ws;
    float* agg = support + (size_t)rows * HH;

    hipMemsetAsync(agg, 0, (size_t)rows * HH * sizeof(float), stream);
    hipMemsetAsync(d_out, 0, (size_t)out_size * sizeof(float), stream);

    k_support<<<dim3((rows + 7) / 8), dim3(256), 0, stream>>>(x, W, support, rows);
    k_scatter<<<dim3((E + 7) / 8), dim3(256), 0, stream>>>(ei, support, agg, E, B);
    k_mlp<<<dim3(1280), dim3(256), 0, stream>>>(agg, b0, W1, b1, W2, b2, W3, b3, out, rows, B);
}

// Round 2
// 668.316 us; speedup vs baseline: 4.6745x; 4.6745x over previous
//
#include <hip/hip_runtime.h>
#include <math.h>

#define NN 50000
#define DD 128
#define HH 128
#define L1 64
#define L2 32
#define OO 10

// ---------------- K1: support[row][h] = sum_d x[row][d] * W[d][h] ----------------
__global__ __launch_bounds__(256) void k_support(
    const float* __restrict__ x, const float* __restrict__ W,
    float* __restrict__ support, int rows)
{
    __shared__ float xs[8][DD];
    const int tid = threadIdx.x;
    const int row0 = blockIdx.x * 8;
    {
        int r = tid >> 5;
        int c4 = (tid & 31) << 2;
        int row = row0 + r;
        float4 v = make_float4(0.f, 0.f, 0.f, 0.f);
        if (row < rows) v = *(const float4*)(x + (size_t)row * DD + c4);
        *(float4*)(&xs[r][c4]) = v;
    }
    __syncthreads();

    const int ln = tid >> 5;
    const int fg = tid & 31;
    const int row = row0 + ln;
    if (row >= rows) return;

    float4 acc = make_float4(0.f, 0.f, 0.f, 0.f);
    const float* wp = W + fg * 4;
    #pragma unroll 4
    for (int k = 0; k < DD; ++k) {
        float xv = xs[ln][k];
        float4 w = *(const float4*)(wp + (size_t)k * HH);
        acc.x += xv * w.x; acc.y += xv * w.y;
        acc.z += xv * w.z; acc.w += xv * w.w;
    }
    *(float4*)(support + (size_t)row * HH + fg * 4) = acc;
}

// ---------------- CSR build: histogram of dst ----------------
__global__ __launch_bounds__(256) void k_hist(
    const int* __restrict__ ei, int* __restrict__ counts, int E)
{
    int e = blockIdx.x * 256 + threadIdx.x;
    if (e < E) atomicAdd(&counts[ei[E + e]], 1);
}

// ---------------- CSR build: exclusive scan over counts (single block) --------
__global__ __launch_bounds__(1024) void k_scan(
    const int* __restrict__ counts, int* __restrict__ offsets, int n)
{
    __shared__ int wsum[16];
    __shared__ int woff[16];
    __shared__ int ctot;
    const int tid = threadIdx.x;
    const int lane = tid & 63;
    const int wv = tid >> 6;
    int running = 0;
    for (int base = 0; base < n; base += 1024) {
        int i = base + tid;
        int v = (i < n) ? counts[i] : 0;
        int x = v;
        #pragma unroll
        for (int d = 1; d < 64; d <<= 1) {
            int t = __shfl_up(x, d);
            if (lane >= d) x += t;
        }
        if (lane == 63) wsum[wv] = x;
        __syncthreads();
        if (wv == 0 && lane < 16) {
            int y = wsum[lane];
            #pragma unroll
            for (int d = 1; d < 16; d <<= 1) {
                int t = __shfl_up(y, d);
                if (lane >= d) y += t;
            }
            woff[lane] = y - wsum[lane];
            if (lane == 15) ctot = y;
        }
        __syncthreads();
        if (i < n) offsets[i] = running + woff[wv] + (x - v);
        running += ctot;
        __syncthreads();
    }
    if (tid == 0) offsets[n] = running;
}

// ---------------- CSR build: bucket src indices by dst ----------------
__global__ __launch_bounds__(256) void k_bucket(
    const int* __restrict__ ei, const int* __restrict__ offsets,
    int* __restrict__ cursor, int* __restrict__ ss, int E)
{
    int e = blockIdx.x * 256 + threadIdx.x;
    if (e < E) {
        int d = ei[E + e];
        int pos = offsets[d] + atomicAdd(&cursor[d], 1);
        ss[pos] = ei[e];
    }
}

// ---------------- K2': agg[b][d] = sum_{in-edges} support[b][src] (gather) ----
// One wave per dst node; lane holds float2 (2 feats) per batch in registers.
__global__ __launch_bounds__(256) void k_agg(
    const float2* __restrict__ support, const int* __restrict__ offsets,
    const int* __restrict__ ss, float2* __restrict__ agg, int nn)
{
    const int tid = threadIdx.x;
    const int lane = tid & 63;
    const int wv = tid >> 6;
    const int d = blockIdx.x * 4 + wv;
    if (d >= nn) return;
    const int s0 = offsets[d], s1 = offsets[d + 1];
    float2 a0 = make_float2(0.f, 0.f), a1 = make_float2(0.f, 0.f);
    for (int i = s0; i < s1; ++i) {
        const int s = ss[i];
        const float2 v0 = support[(size_t)s * 64 + lane];
        const float2 v1 = support[((size_t)nn + s) * 64 + lane];
        a0.x += v0.x; a0.y += v0.y;
        a1.x += v1.x; a1.y += v1.y;
    }
    agg[(size_t)d * 64 + lane] = a0;
    agg[((size_t)nn + d) * 64 + lane] = a1;
}

// ---------------- Fallback scatter (if ws too small for CSR) ----------------
__global__ __launch_bounds__(256) void k_scatter(
    const int* __restrict__ ei, const float* __restrict__ support,
    float* __restrict__ agg, int E, int B)
{
    const int tid = threadIdx.x;
    const int eg = tid >> 5;
    const int t4 = (tid & 31) << 2;
    const int e = blockIdx.x * 8 + eg;
    if (e >= E) return;
    const int src = ei[e];
    const int dst = ei[E + e];
    for (int b = 0; b < B; ++b) {
        const float4 v = *(const float4*)(support + ((size_t)b * NN + src) * HH + t4);
        float* ap = agg + ((size_t)b * NN + dst) * HH + t4;
        unsafeAtomicAdd(ap + 0, v.x);
        unsafeAtomicAdd(ap + 1, v.y);
        unsafeAtomicAdd(ap + 2, v.z);
        unsafeAtomicAdd(ap + 3, v.w);
    }
}

// ---------------- K3: h=gelu(agg+b); MLP 128->64->32->10; mean over nodes ------
__global__ __launch_bounds__(256) void k_mlp(
    const float* __restrict__ agg,
    const float* __restrict__ b0v, const float* __restrict__ W1, const float* __restrict__ b1v,
    const float* __restrict__ W2, const float* __restrict__ b2v,
    const float* __restrict__ W3, const float* __restrict__ b3v,
    float* __restrict__ out, int rows, int B)
{
    __shared__ float w1s[HH * L1];
    __shared__ float w2s[L1 * L2];
    __shared__ float w3s[L2 * OO];
    __shared__ float b0s[HH], b1s[L1], b2s[L2], b3s[OO];
    __shared__ float hs[4][HH];
    __shared__ float h1s[4][L1];
    __shared__ float h2s[4][L2];
    __shared__ float oacc[2 * OO];

    const int tid = threadIdx.x;
    for (int i = tid; i < HH * L1; i += 256) w1s[i] = W1[i];
    for (int i = tid; i < L1 * L2; i += 256) w2s[i] = W2[i];
    for (int i = tid; i < L2 * OO; i += 256) w3s[i] = W3[i];
    if (tid < HH) b0s[tid] = b0v[tid];
    if (tid < L1) b1s[tid] = b1v[tid];
    if (tid < L2) b2s[tid] = b2v[tid];
    if (tid < OO) b3s[tid] = b3v[tid];
    if (tid < 2 * OO) oacc[tid] = 0.f;
    __syncthreads();

    const int ln = tid >> 6;
    const int lane = tid & 63;

    const int ngroups = (rows + 3) >> 2;
    for (int g = blockIdx.x; g < ngroups; g += gridDim.x) {
        const int row = g * 4 + ln;
        const bool valid = row < rows;
        if (valid) {
            float a0 = agg[(size_t)row * HH + lane] + b0s[lane];
            float a1 = agg[(size_t)row * HH + 64 + lane] + b0s[64 + lane];
            hs[ln][lane]      = 0.5f * a0 * (1.f + erff(a0 * 0.70710678118654752f));
            hs[ln][64 + lane] = 0.5f * a1 * (1.f + erff(a1 * 0.70710678118654752f));
        }
        __syncthreads();
        if (valid) {
            float acc = b1s[lane];
            #pragma unroll 8
            for (int j = 0; j < HH; ++j) acc += hs[ln][j] * w1s[j * L1 + lane];
            h1s[ln][lane] = fmaxf(acc, 0.f);
        }
        __syncthreads();
        if (valid && lane < L2) {
            float acc = b2s[lane];
            #pragma unroll 8
            for (int j = 0; j < L1; ++j) acc += h1s[ln][j] * w2s[j * L2 + lane];
            h2s[ln][lane] = fmaxf(acc, 0.f);
        }
        __syncthreads();
        if (valid && lane < OO) {
            float acc = b3s[lane];
            #pragma unroll
            for (int j = 0; j < L2; ++j) acc += h2s[ln][j] * w3s[j * OO + lane];
            const int batch = row / NN;
            atomicAdd(&oacc[batch * OO + lane], acc);
        }
        __syncthreads();
    }
    if (tid < B * OO) {
        atomicAdd(out + tid, oacc[tid] * (1.0f / (float)NN));
    }
}

extern "C" void kernel_launch(void* const* d_in, const int* in_sizes, int n_in,
                              void* d_out, int out_size, void* d_ws, size_t ws_size,
                              hipStream_t stream) {
    const float* x  = (const float*)d_in[0];
    const int*   ei = (const int*)d_in[1];
    const float* W  = (const float*)d_in[2];
    const float* b0 = (const float*)d_in[3];
    const float* W1 = (const float*)d_in[4];
    const float* b1 = (const float*)d_in[5];
    const float* W2 = (const float*)d_in[6];
    const float* b2 = (const float*)d_in[7];
    const float* W3 = (const float*)d_in[8];
    const float* b3 = (const float*)d_in[9];
    float* out = (float*)d_out;

    const int B = in_sizes[0] / (NN * DD);   // 2
    const int E = in_sizes[1] / 2;           // 800000
    const int rows = B * NN;                 // 100000

    // workspace layout
    float* support = (float*)d_ws;                               // rows*HH f32
    float* agg     = support + (size_t)rows * HH;                // rows*HH f32
    int*   counts  = (int*)(agg + (size_t)rows * HH);            // NN
    int*   cursor  = counts + NN;                                // NN
    int*   offsets = cursor + NN;                                // NN+1
    int*   ss      = offsets + NN + 1;                           // E
    const size_t need = ((size_t)rows * HH * 2) * sizeof(float)
                      + ((size_t)NN * 2 + NN + 1 + E) * sizeof(int);

    hipMemsetAsync(d_out, 0, (size_t)out_size * sizeof(float), stream);
    k_support<<<dim3((rows + 7) / 8), dim3(256), 0, stream>>>(x, W, support, rows);

    if (ws_size >= need) {
        // CSR gather path: no feature atomics
        hipMemsetAsync(counts, 0, (size_t)NN * 2 * sizeof(int), stream);  // counts+cursor
        k_hist<<<dim3((E + 255) / 256), dim3(256), 0, stream>>>(ei, counts, E);
        k_scan<<<dim3(1), dim3(1024), 0, stream>>>(counts, offsets, NN);
        k_bucket<<<dim3((E + 255) / 256), dim3(256), 0, stream>>>(ei, offsets, cursor, ss, E);
        k_agg<<<dim3((NN + 3) / 4), dim3(256), 0, stream>>>(
            (const float2*)support, offsets, ss, (float2*)agg, NN);
    } else {
        hipMemsetAsync(agg, 0, (size_t)rows * HH * sizeof(float), stream);
        k_scatter<<<dim3((E + 7) / 8), dim3(256), 0, stream>>>(ei, support, agg, E, B);
    }

    k_mlp<<<dim3(1280), dim3(256), 0, stream>>>(agg, b0, W1, b1, W2, b2, W3, b3, out, rows, B);
}

// Round 3
// 643.283 us; speedup vs baseline: 4.8564x; 1.0389x over previous
//
#include <hip/hip_runtime.h>
#include <math.h>

#define NN 50000
#define DD 128
#define HH 128
#define L1 64
#define L2 32
#define OO 10

// ---------------- K1: support = x @ W  (LDS-tiled, 64 rows/block) ----------------
// 256 threads; xs = 64x128 rows tile (32 KB); W staged in two 64-k halves (32 KB).
// Thread: 8 rows x 4 cols, all LDS reads b128 with <=2-way bank aliasing (free).
__global__ __launch_bounds__(256) void k_support(
    const float* __restrict__ x, const float* __restrict__ W,
    float* __restrict__ support, int rows)
{
    __shared__ float xs[64][DD];   // 32 KB
    __shared__ float wh[64][HH];   // 32 KB (one 64-k half of W)
    const int tid = threadIdx.x;
    const int row0 = blockIdx.x * 64;

    // stage x tile (guarded, coalesced float4)
    for (int u = tid * 4; u < 64 * DD; u += 256 * 4) {
        const int r = u >> 7, c = u & 127;
        float4 v = make_float4(0.f, 0.f, 0.f, 0.f);
        if (row0 + r < rows) v = *(const float4*)(x + (size_t)(row0 + r) * DD + c);
        *(float4*)(&xs[r][c]) = v;
    }

    const int cg = tid & 31;   // 4-col group: cols cg*4..+3
    const int rg = tid >> 5;   // 0..7: rows q*32 + rg*4 + i
    float4 acc[8];
    #pragma unroll
    for (int i = 0; i < 8; ++i) acc[i] = make_float4(0.f, 0.f, 0.f, 0.f);

    for (int p = 0; p < 2; ++p) {
        __syncthreads();   // protect wh reuse (and xs completion on first pass)
        for (int u = tid * 4; u < 64 * HH; u += 256 * 4) {
            const int r = u >> 7, c = u & 127;
            *(float4*)(&wh[r][c]) = *(const float4*)(W + (size_t)(p * 64 + r) * HH + c);
        }
        __syncthreads();
        #pragma unroll 2
        for (int k = 0; k < 64; k += 4) {
            float4 wv[4];
            #pragma unroll
            for (int jj = 0; jj < 4; ++jj) wv[jj] = *(const float4*)(&wh[k + jj][cg * 4]);
            #pragma unroll
            for (int q = 0; q < 2; ++q) {
                #pragma unroll
                for (int i = 0; i < 4; ++i) {
                    const float4 xv = *(const float4*)(&xs[q * 32 + rg * 4 + i][p * 64 + k]);
                    float4* a = &acc[q * 4 + i];
                    a->x = fmaf(xv.x, wv[0].x, fmaf(xv.y, wv[1].x, fmaf(xv.z, wv[2].x, fmaf(xv.w, wv[3].x, a->x))));
                    a->y = fmaf(xv.x, wv[0].y, fmaf(xv.y, wv[1].y, fmaf(xv.z, wv[2].y, fmaf(xv.w, wv[3].y, a->y))));
                    a->z = fmaf(xv.x, wv[0].z, fmaf(xv.y, wv[1].z, fmaf(xv.z, wv[2].z, fmaf(xv.w, wv[3].z, a->z))));
                    a->w = fmaf(xv.x, wv[0].w, fmaf(xv.y, wv[1].w, fmaf(xv.z, wv[2].w, fmaf(xv.w, wv[3].w, a->w))));
                }
            }
        }
    }

    #pragma unroll
    for (int q = 0; q < 2; ++q)
        #pragma unroll
        for (int i = 0; i < 4; ++i) {
            const int r = row0 + q * 32 + rg * 4 + i;
            if (r < rows) *(float4*)(support + (size_t)r * HH + cg * 4) = acc[q * 4 + i];
        }
}

// ---------------- CSR build: histogram of dst ----------------
__global__ __launch_bounds__(256) void k_hist(
    const int* __restrict__ ei, int* __restrict__ counts, int E)
{
    int e = blockIdx.x * 256 + threadIdx.x;
    if (e < E) atomicAdd(&counts[ei[E + e]], 1);
}

// ---------------- CSR build: exclusive scan (single block) ----------------
__global__ __launch_bounds__(1024) void k_scan(
    const int* __restrict__ counts, int* __restrict__ offsets, int n)
{
    __shared__ int wsum[16];
    __shared__ int woff[16];
    __shared__ int ctot;
    const int tid = threadIdx.x;
    const int lane = tid & 63;
    const int wv = tid >> 6;
    int running = 0;
    for (int base = 0; base < n; base += 1024) {
        int i = base + tid;
        int v = (i < n) ? counts[i] : 0;
        int x = v;
        #pragma unroll
        for (int d = 1; d < 64; d <<= 1) {
            int t = __shfl_up(x, d);
            if (lane >= d) x += t;
        }
        if (lane == 63) wsum[wv] = x;
        __syncthreads();
        if (wv == 0 && lane < 16) {
            int y = wsum[lane];
            #pragma unroll
            for (int d = 1; d < 16; d <<= 1) {
                int t = __shfl_up(y, d);
                if (lane >= d) y += t;
            }
            woff[lane] = y - wsum[lane];
            if (lane == 15) ctot = y;
        }
        __syncthreads();
        if (i < n) offsets[i] = running + woff[wv] + (x - v);
        running += ctot;
        __syncthreads();
    }
    if (tid == 0) offsets[n] = running;
}

// ---------------- CSR build: bucket src indices by dst ----------------
__global__ __launch_bounds__(256) void k_bucket(
    const int* __restrict__ ei, const int* __restrict__ offsets,
    int* __restrict__ cursor, int* __restrict__ ss, int E)
{
    int e = blockIdx.x * 256 + threadIdx.x;
    if (e < E) {
        int d = ei[E + e];
        int pos = offsets[d] + atomicAdd(&cursor[d], 1);
        ss[pos] = ei[e];
    }
}

// ---------------- K2': gather-aggregate. One wave per dst; lanes 0-31 batch0,
// lanes 32-63 batch1, float4 per lane (one dwordx4 covers both batches). ------
__global__ __launch_bounds__(256) void k_agg(
    const float4* __restrict__ sup4, const int* __restrict__ offsets,
    const int* __restrict__ ss, float4* __restrict__ agg4, int nn)
{
    const int tid = threadIdx.x;
    const int lane = tid & 63;
    const int wv = tid >> 6;
    const int d = blockIdx.x * 4 + wv;
    if (d >= nn) return;
    const int b = lane >> 5;          // batch
    const int f = lane & 31;          // float4 index within row (32*16B = 512B)
    const size_t bbase = (size_t)b * nn * 32;
    const int s0 = offsets[d], s1 = offsets[d + 1];
    float4 a = make_float4(0.f, 0.f, 0.f, 0.f);
    for (int i = s0; i < s1; ++i) {
        const int s = ss[i];
        const float4 v = sup4[bbase + (size_t)s * 32 + f];
        a.x += v.x; a.y += v.y; a.z += v.z; a.w += v.w;
    }
    agg4[bbase + (size_t)d * 32 + f] = a;
}

// ---------------- Fallback scatter (if ws too small for CSR) ----------------
__global__ __launch_bounds__(256) void k_scatter(
    const int* __restrict__ ei, const float* __restrict__ support,
    float* __restrict__ agg, int E, int B)
{
    const int tid = threadIdx.x;
    const int eg = tid >> 5;
    const int t4 = (tid & 31) << 2;
    const int e = blockIdx.x * 8 + eg;
    if (e >= E) return;
    const int src = ei[e];
    const int dst = ei[E + e];
    for (int b = 0; b < B; ++b) {
        const float4 v = *(const float4*)(support + ((size_t)b * NN + src) * HH + t4);
        float* ap = agg + ((size_t)b * NN + dst) * HH + t4;
        unsafeAtomicAdd(ap + 0, v.x);
        unsafeAtomicAdd(ap + 1, v.y);
        unsafeAtomicAdd(ap + 2, v.z);
        unsafeAtomicAdd(ap + 3, v.w);
    }
}

// ---------------- K3: gelu + MLP(128->64->32) + per-block h2 column sums ------
// 32 rows/block, 256 threads. Layer3 is linear => folded into k_final via
// mean(h2)@W3. LDS ~55 KB -> 2 blocks/CU.
__global__ __launch_bounds__(256) void k_mlp(
    const float* __restrict__ agg, const float* __restrict__ b0v,
    const float* __restrict__ W1, const float* __restrict__ b1v,
    const float* __restrict__ W2, const float* __restrict__ b2v,
    float* __restrict__ partials, int rows)
{
    __shared__ float w1h[64][L1];        // 16 KB, one 64-k half of W1
    __shared__ float w2s[L1][L2];        // 8 KB
    __shared__ float hs[32][DD + 8];     // stride 136: 2-way only, 16B-aligned
    __shared__ float h1s[32][L1 + 4];    // stride 68
    __shared__ float h2s[32][L2 + 4];    // stride 36
    __shared__ float b0s[DD], b1s[L1], b2s[L2];
    __shared__ float oacc[64];           // [batch][32] column sums

    const int tid = threadIdx.x;
    const int row0 = blockIdx.x * 32;

    // stage W2, biases, W1 half 0; gelu(agg + b0) -> hs; zero oacc
    for (int u = tid * 4; u < L1 * L2; u += 1024)
        *(float4*)(&w2s[u >> 5][u & 31]) = *(const float4*)(W2 + u);
    if (tid < DD) b0s[tid] = b0v[tid];
    if (tid < L1) b1s[tid] = b1v[tid];
    if (tid < L2) b2s[tid] = b2v[tid];
    if (tid < 64) oacc[tid] = 0.f;
    for (int u = tid * 4; u < 64 * L1; u += 1024)
        *(float4*)(&w1h[u >> 6][u & 63]) = *(const float4*)(W1 + u);
    for (int u = tid * 4; u < 32 * DD; u += 1024) {
        const int r = u >> 7, c = u & 127;
        float4 v = make_float4(0.f, 0.f, 0.f, 0.f);
        if (row0 + r < rows) v = *(const float4*)(agg + (size_t)(row0 + r) * DD + c);
        const float4 bb = *(const float4*)(&b0s[c]);
        float a0 = v.x + bb.x, a1 = v.y + bb.y, a2 = v.z + bb.z, a3 = v.w + bb.w;
        float4 g;
        g.x = 0.5f * a0 * (1.f + erff(a0 * 0.70710678118654752f));
        g.y = 0.5f * a1 * (1.f + erff(a1 * 0.70710678118654752f));
        g.z = 0.5f * a2 * (1.f + erff(a2 * 0.70710678118654752f));
        g.w = 0.5f * a3 * (1.f + erff(a3 * 0.70710678118654752f));
        *(float4*)(&hs[r][c]) = g;
    }
    __syncthreads();

    // layer1: thread = 2 rows x 4 cols
    const int cg = tid & 15;    // cols cg*4..+3 (of 64)
    const int rg = tid >> 4;    // 0..15: rows rg*2+{0,1}
    float4 acc0 = *(const float4*)(&b1s[cg * 4]);
    float4 acc1 = acc0;
    #pragma unroll 4
    for (int j = 0; j < 64; j += 4) {
        float4 wv[4];
        #pragma unroll
        for (int jj = 0; jj < 4; ++jj) wv[jj] = *(const float4*)(&w1h[j + jj][cg * 4]);
        const float4 h0 = *(const float4*)(&hs[rg * 2 + 0][j]);
        const float4 h1 = *(const float4*)(&hs[rg * 2 + 1][j]);
        acc0.x = fmaf(h0.x, wv[0].x, fmaf(h0.y, wv[1].x, fmaf(h0.z, wv[2].x, fmaf(h0.w, wv[3].x, acc0.x))));
        acc0.y = fmaf(h0.x, wv[0].y, fmaf(h0.y, wv[1].y, fmaf(h0.z, wv[2].y, fmaf(h0.w, wv[3].y, acc0.y))));
        acc0.z = fmaf(h0.x, wv[0].z, fmaf(h0.y, wv[1].z, fmaf(h0.z, wv[2].z, fmaf(h0.w, wv[3].z, acc0.z))));
        acc0.w = fmaf(h0.x, wv[0].w, fmaf(h0.y, wv[1].w, fmaf(h0.z, wv[2].w, fmaf(h0.w, wv[3].w, acc0.w))));
        acc1.x = fmaf(h1.x, wv[0].x, fmaf(h1.y, wv[1].x, fmaf(h1.z, wv[2].x, fmaf(h1.w, wv[3].x, acc1.x))));
        acc1.y = fmaf(h1.x, wv[0].y, fmaf(h1.y, wv[1].y, fmaf(h1.z, wv[2].y, fmaf(h1.w, wv[3].y, acc1.y))));
        acc1.z = fmaf(h1.x, wv[0].z, fmaf(h1.y, wv[1].z, fmaf(h1.z, wv[2].z, fmaf(h1.w, wv[3].z, acc1.z))));
        acc1.w = fmaf(h1.x, wv[0].w, fmaf(h1.y, wv[1].w, fmaf(h1.z, wv[2].w, fmaf(h1.w, wv[3].w, acc1.w))));
    }
    __syncthreads();
    // stage W1 half 1
    for (int u = tid * 4; u < 64 * L1; u += 1024)
        *(float4*)(&w1h[u >> 6][u & 63]) = *(const float4*)(W1 + 64 * L1 + u);
    __syncthreads();
    #pragma unroll 4
    for (int j = 0; j < 64; j += 4) {
        float4 wv[4];
        #pragma unroll
        for (int jj = 0; jj < 4; ++jj) wv[jj] = *(const float4*)(&w1h[j + jj][cg * 4]);
        const float4 h0 = *(const float4*)(&hs[rg * 2 + 0][64 + j]);
        const float4 h1 = *(const float4*)(&hs[rg * 2 + 1][64 + j]);
        acc0.x = fmaf(h0.x, wv[0].x, fmaf(h0.y, wv[1].x, fmaf(h0.z, wv[2].x, fmaf(h0.w, wv[3].x, acc0.x))));
        acc0.y = fmaf(h0.x, wv[0].y, fmaf(h0.y, wv[1].y, fmaf(h0.z, wv[2].y, fmaf(h0.w, wv[3].y, acc0.y))));
        acc0.z = fmaf(h0.x, wv[0].z, fmaf(h0.y, wv[1].z, fmaf(h0.z, wv[2].z, fmaf(h0.w, wv[3].z, acc0.z))));
        acc0.w = fmaf(h0.x, wv[0].w, fmaf(h0.y, wv[1].w, fmaf(h0.z, wv[2].w, fmaf(h0.w, wv[3].w, acc0.w))));
        acc1.x = fmaf(h1.x, wv[0].x, fmaf(h1.y, wv[1].x, fmaf(h1.z, wv[2].x, fmaf(h1.w, wv[3].x, acc1.x))));
        acc1.y = fmaf(h1.x, wv[0].y, fmaf(h1.y, wv[1].y, fmaf(h1.z, wv[2].y, fmaf(h1.w, wv[3].y, acc1.y))));
        acc1.z = fmaf(h1.x, wv[0].z, fmaf(h1.y, wv[1].z, fmaf(h1.z, wv[2].z, fmaf(h1.w, wv[3].z, acc1.z))));
        acc1.w = fmaf(h1.x, wv[0].w, fmaf(h1.y, wv[1].w, fmaf(h1.z, wv[2].w, fmaf(h1.w, wv[3].w, acc1.w))));
    }
    acc0.x = fmaxf(acc0.x, 0.f); acc0.y = fmaxf(acc0.y, 0.f);
    acc0.z = fmaxf(acc0.z, 0.f); acc0.w = fmaxf(acc0.w, 0.f);
    acc1.x = fmaxf(acc1.x, 0.f); acc1.y = fmaxf(acc1.y, 0.f);
    acc1.z = fmaxf(acc1.z, 0.f); acc1.w = fmaxf(acc1.w, 0.f);
    *(float4*)(&h1s[rg * 2 + 0][cg * 4]) = acc0;
    *(float4*)(&h1s[rg * 2 + 1][cg * 4]) = acc1;
    __syncthreads();

    // layer2: thread = 1 row x 4 cols
    {
        const int cg2 = tid & 7;    // cols cg2*4..+3 (of 32)
        const int r2 = tid >> 3;    // row 0..31
        float4 a = *(const float4*)(&b2s[cg2 * 4]);
        #pragma unroll 4
        for (int j = 0; j < L1; j += 4) {
            float4 wv[4];
            #pragma unroll
            for (int jj = 0; jj < 4; ++jj) wv[jj] = *(const float4*)(&w2s[j + jj][cg2 * 4]);
            const float4 hv = *(const float4*)(&h1s[r2][j]);
            a.x = fmaf(hv.x, wv[0].x, fmaf(hv.y, wv[1].x, fmaf(hv.z, wv[2].x, fmaf(hv.w, wv[3].x, a.x))));
            a.y = fmaf(hv.x, wv[0].y, fmaf(hv.y, wv[1].y, fmaf(hv.z, wv[2].y, fmaf(hv.w, wv[3].y, a.y))));
            a.z = fmaf(hv.x, wv[0].z, fmaf(hv.y, wv[1].z, fmaf(hv.z, wv[2].z, fmaf(hv.w, wv[3].z, a.z))));
            a.w = fmaf(hv.x, wv[0].w, fmaf(hv.y, wv[1].w, fmaf(hv.z, wv[2].w, fmaf(hv.w, wv[3].w, a.w))));
        }
        a.x = fmaxf(a.x, 0.f); a.y = fmaxf(a.y, 0.f);
        a.z = fmaxf(a.z, 0.f); a.w = fmaxf(a.w, 0.f);
        *(float4*)(&h2s[r2][cg2 * 4]) = a;
    }
    __syncthreads();

    // column sums of h2 per batch -> oacc
    {
        const int c = tid & 31;
        const int g = tid >> 5;   // 0..7, 4 rows each
        float p0 = 0.f, p1 = 0.f;
        #pragma unroll
        for (int i = 0; i < 4; ++i) {
            const int r = g * 4 + i;
            const int grow = row0 + r;
            if (grow < rows) {
                const float v = h2s[r][c];
                if (grow >= NN) p1 += v; else p0 += v;
            }
        }
        if (p0 != 0.f) atomicAdd(&oacc[c], p0);
        if (p1 != 0.f) atomicAdd(&oacc[32 + c], p1);
    }
    __syncthreads();
    if (tid < 64) partials[(size_t)blockIdx.x * 64 + tid] = oacc[tid];
}

// ---------------- K4: reduce partials, apply layer3 ----------------
__global__ __launch_bounds__(256) void k_final(
    const float* __restrict__ partials, const float* __restrict__ W3,
    const float* __restrict__ b3v, float* __restrict__ out, int nblk)
{
    __shared__ float psum[4][64];
    __shared__ float hb[64];
    const int t = threadIdx.x & 63;
    const int seg = threadIdx.x >> 6;
    float s = 0.f;
    for (int g = seg; g < nblk; g += 4) s += partials[(size_t)g * 64 + t];
    psum[seg][t] = s;
    __syncthreads();
    if (threadIdx.x < 64) hb[threadIdx.x] = psum[0][threadIdx.x] + psum[1][threadIdx.x]
                                          + psum[2][threadIdx.x] + psum[3][threadIdx.x];
    __syncthreads();
    if (threadIdx.x < 2 * OO) {
        const int b = threadIdx.x / OO, o = threadIdx.x % OO;
        float acc = b3v[o];
        const float inv = 1.0f / (float)NN;
        #pragma unroll
        for (int j = 0; j < L2; ++j) acc += (hb[b * 32 + j] * inv) * W3[j * OO + o];
        out[threadIdx.x] = acc;
    }
}

extern "C" void kernel_launch(void* const* d_in, const int* in_sizes, int n_in,
                              void* d_out, int out_size, void* d_ws, size_t ws_size,
                              hipStream_t stream) {
    const float* x  = (const float*)d_in[0];
    const int*   ei = (const int*)d_in[1];
    const float* W  = (const float*)d_in[2];
    const float* b0 = (const float*)d_in[3];
    const float* W1 = (const float*)d_in[4];
    const float* b1 = (const float*)d_in[5];
    const float* W2 = (const float*)d_in[6];
    const float* b2 = (const float*)d_in[7];
    const float* W3 = (const float*)d_in[8];
    const float* b3 = (const float*)d_in[9];
    float* out = (float*)d_out;

    const int B = in_sizes[0] / (NN * DD);   // 2
    const int E = in_sizes[1] / 2;           // 800000
    const int rows = B * NN;                 // 100000
    const int nblk_mlp = (rows + 31) / 32;   // 3125

    // workspace layout
    float* support  = (float*)d_ws;                                  // rows*HH
    float* agg      = support + (size_t)rows * HH;                   // rows*HH
    float* partials = agg + (size_t)rows * HH;                       // nblk_mlp*64
    int*   counts   = (int*)(partials + (size_t)nblk_mlp * 64);      // NN
    int*   cursor   = counts + NN;                                   // NN
    int*   offsets  = cursor + NN;                                   // NN+1
    int*   ss       = offsets + NN + 1;                              // E
    const size_t need = ((size_t)rows * HH * 2 + (size_t)nblk_mlp * 64) * sizeof(float)
                      + ((size_t)NN * 3 + 1 + E) * sizeof(int);

    k_support<<<dim3((rows + 63) / 64), dim3(256), 0, stream>>>(x, W, support, rows);

    if (ws_size >= need) {
        hipMemsetAsync(counts, 0, (size_t)NN * 2 * sizeof(int), stream);  // counts+cursor
        k_hist<<<dim3((E + 255) / 256), dim3(256), 0, stream>>>(ei, counts, E);
        k_scan<<<dim3(1), dim3(1024), 0, stream>>>(counts, offsets, NN);
        k_bucket<<<dim3((E + 255) / 256), dim3(256), 0, stream>>>(ei, offsets, cursor, ss, E);
        k_agg<<<dim3((NN + 3) / 4), dim3(256), 0, stream>>>(
            (const float4*)support, offsets, ss, (float4*)agg, NN);
    } else {
        hipMemsetAsync(agg, 0, (size_t)rows * HH * sizeof(float), stream);
        k_scatter<<<dim3((E + 7) / 8), dim3(256), 0, stream>>>(ei, support, agg, E, B);
    }

    k_mlp<<<dim3(nblk_mlp), dim3(256), 0, stream>>>(agg, b0, W1, b1, W2, b2, partials, rows);
    k_final<<<dim3(1), dim3(256), 0, stream>>>(partials, W3, b3, out, nblk_mlp);
}

// Round 4
// 414.478 us; speedup vs baseline: 7.5373x; 1.5520x over previous
//
#include <hip/hip_runtime.h>
#include <math.h>

#define NN 50000
#define DD 128
#define HH 128
#define L1 64
#define L2 32
#define OO 10

// ---------------- K1: support = x @ W  (LDS-tiled, 64 rows/block) ----------------
__global__ __launch_bounds__(256) void k_support(
    const float* __restrict__ x, const float* __restrict__ W,
    float* __restrict__ support, int rows)
{
    __shared__ float xs[64][DD];   // 32 KB
    __shared__ float wh[64][HH];   // 32 KB (one 64-k half of W)
    const int tid = threadIdx.x;
    const int row0 = blockIdx.x * 64;

    for (int u = tid * 4; u < 64 * DD; u += 256 * 4) {
        const int r = u >> 7, c = u & 127;
        float4 v = make_float4(0.f, 0.f, 0.f, 0.f);
        if (row0 + r < rows) v = *(const float4*)(x + (size_t)(row0 + r) * DD + c);
        *(float4*)(&xs[r][c]) = v;
    }

    const int cg = tid & 31;
    const int rg = tid >> 5;
    float4 acc[8];
    #pragma unroll
    for (int i = 0; i < 8; ++i) acc[i] = make_float4(0.f, 0.f, 0.f, 0.f);

    for (int p = 0; p < 2; ++p) {
        __syncthreads();
        for (int u = tid * 4; u < 64 * HH; u += 256 * 4) {
            const int r = u >> 7, c = u & 127;
            *(float4*)(&wh[r][c]) = *(const float4*)(W + (size_t)(p * 64 + r) * HH + c);
        }
        __syncthreads();
        #pragma unroll 2
        for (int k = 0; k < 64; k += 4) {
            float4 wv[4];
            #pragma unroll
            for (int jj = 0; jj < 4; ++jj) wv[jj] = *(const float4*)(&wh[k + jj][cg * 4]);
            #pragma unroll
            for (int q = 0; q < 2; ++q) {
                #pragma unroll
                for (int i = 0; i < 4; ++i) {
                    const float4 xv = *(const float4*)(&xs[q * 32 + rg * 4 + i][p * 64 + k]);
                    float4* a = &acc[q * 4 + i];
                    a->x = fmaf(xv.x, wv[0].x, fmaf(xv.y, wv[1].x, fmaf(xv.z, wv[2].x, fmaf(xv.w, wv[3].x, a->x))));
                    a->y = fmaf(xv.x, wv[0].y, fmaf(xv.y, wv[1].y, fmaf(xv.z, wv[2].y, fmaf(xv.w, wv[3].y, a->y))));
                    a->z = fmaf(xv.x, wv[0].z, fmaf(xv.y, wv[1].z, fmaf(xv.z, wv[2].z, fmaf(xv.w, wv[3].z, a->z))));
                    a->w = fmaf(xv.x, wv[0].w, fmaf(xv.y, wv[1].w, fmaf(xv.z, wv[2].w, fmaf(xv.w, wv[3].w, a->w))));
                }
            }
        }
    }

    #pragma unroll
    for (int q = 0; q < 2; ++q)
        #pragma unroll
        for (int i = 0; i < 4; ++i) {
            const int r = row0 + q * 32 + rg * 4 + i;
            if (r < rows) *(float4*)(support + (size_t)r * HH + cg * 4) = acc[q * 4 + i];
        }
}

// ---------------- CSR build: histogram of dst ----------------
__global__ __launch_bounds__(256) void k_hist(
    const int* __restrict__ ei, int* __restrict__ counts, int E)
{
    int e = blockIdx.x * 256 + threadIdx.x;
    if (e < E) atomicAdd(&counts[ei[E + e]], 1);
}

// ---------------- multi-block scan, stage 1: block-local exclusive scan --------
__global__ __launch_bounds__(1024) void k_scan1(
    const int* __restrict__ counts, int* __restrict__ offsets,
    int* __restrict__ blksum, int n)
{
    __shared__ int wsum[16], woff[16];
    const int tid = threadIdx.x, lane = tid & 63, wv = tid >> 6;
    const int i = blockIdx.x * 1024 + tid;
    int v = (i < n) ? counts[i] : 0;
    int x = v;
    #pragma unroll
    for (int d = 1; d < 64; d <<= 1) { int t = __shfl_up(x, d); if (lane >= d) x += t; }
    if (lane == 63) wsum[wv] = x;
    __syncthreads();
    if (wv == 0 && lane < 16) {
        int y = wsum[lane];
        #pragma unroll
        for (int d = 1; d < 16; d <<= 1) { int t = __shfl_up(y, d); if (lane >= d) y += t; }
        woff[lane] = y - wsum[lane];
        if (lane == 15) blksum[blockIdx.x] = y;
    }
    __syncthreads();
    if (i < n) offsets[i] = woff[wv] + (x - v);
}

// ---------------- multi-block scan, stage 2: add block bases ----------------
__global__ __launch_bounds__(1024) void k_scan2(
    int* __restrict__ offsets, const int* __restrict__ blksum, int nblk, int n)
{
    __shared__ int base_sh, tot_sh;
    const int tid = threadIdx.x, lane = tid & 63, wv = tid >> 6;
    if (wv == 0) {
        int v = (lane < nblk) ? blksum[lane] : 0;
        int x = v;
        #pragma unroll
        for (int d = 1; d < 64; d <<= 1) { int t = __shfl_up(x, d); if (lane >= d) x += t; }
        int incl = __shfl(x, blockIdx.x);
        int own  = __shfl(v, blockIdx.x);
        int tot  = __shfl(x, nblk - 1);
        if (lane == 0) { base_sh = incl - own; tot_sh = tot; }
    }
    __syncthreads();
    const int i = blockIdx.x * 1024 + tid;
    if (i < n) offsets[i] += base_sh;
    if (blockIdx.x == nblk - 1 && tid == 0) offsets[n] = tot_sh;
}

// ---------------- CSR build: bucket src indices by dst ----------------
__global__ __launch_bounds__(256) void k_bucket(
    const int* __restrict__ ei, const int* __restrict__ offsets,
    int* __restrict__ cursor, int* __restrict__ ss, int E)
{
    int e = blockIdx.x * 256 + threadIdx.x;
    if (e < E) {
        int d = ei[E + e];
        int pos = offsets[d] + atomicAdd(&cursor[d], 1);
        ss[pos] = ei[e];
    }
}

// ---------------- K2': gather-aggregate, unrolled x2 with dual accumulators ----
__global__ __launch_bounds__(256) void k_agg(
    const float4* __restrict__ sup4, const int* __restrict__ offsets,
    const int* __restrict__ ss, float4* __restrict__ agg4, int nn)
{
    const int tid = threadIdx.x;
    const int lane = tid & 63;
    const int wv = tid >> 6;
    const int d = blockIdx.x * 4 + wv;
    if (d >= nn) return;
    const int b = lane >> 5;
    const int f = lane & 31;
    const size_t bbase = (size_t)b * nn * 32;
    const int s0 = offsets[d], s1 = offsets[d + 1];
    float4 a = make_float4(0.f, 0.f, 0.f, 0.f);
    float4 a2 = make_float4(0.f, 0.f, 0.f, 0.f);
    int i = s0;
    for (; i + 2 <= s1; i += 2) {
        const int sA = ss[i], sB = ss[i + 1];
        const float4 vA = sup4[bbase + (size_t)sA * 32 + f];
        const float4 vB = sup4[bbase + (size_t)sB * 32 + f];
        a.x += vA.x;  a.y += vA.y;  a.z += vA.z;  a.w += vA.w;
        a2.x += vB.x; a2.y += vB.y; a2.z += vB.z; a2.w += vB.w;
    }
    if (i < s1) {
        const float4 v = sup4[bbase + (size_t)ss[i] * 32 + f];
        a.x += v.x; a.y += v.y; a.z += v.z; a.w += v.w;
    }
    a.x += a2.x; a.y += a2.y; a.z += a2.z; a.w += a2.w;
    agg4[bbase + (size_t)d * 32 + f] = a;
}

// ---------------- Fallback scatter (if ws too small for CSR) ----------------
__global__ __launch_bounds__(256) void k_scatter(
    const int* __restrict__ ei, const float* __restrict__ support,
    float* __restrict__ agg, int E, int B)
{
    const int tid = threadIdx.x;
    const int eg = tid >> 5;
    const int t4 = (tid & 31) << 2;
    const int e = blockIdx.x * 8 + eg;
    if (e >= E) return;
    const int src = ei[e];
    const int dst = ei[E + e];
    for (int b = 0; b < B; ++b) {
        const float4 v = *(const float4*)(support + ((size_t)b * NN + src) * HH + t4);
        float* ap = agg + ((size_t)b * NN + dst) * HH + t4;
        unsafeAtomicAdd(ap + 0, v.x);
        unsafeAtomicAdd(ap + 1, v.y);
        unsafeAtomicAdd(ap + 2, v.z);
        unsafeAtomicAdd(ap + 3, v.w);
    }
}

// ---------------- K3: gelu + MLP(128->64->32) + per-block h2 column sums ------
// 32 rows/block, 256 threads, W1 staged whole (LDS ~72 KB -> 2 blocks/CU).
__global__ __launch_bounds__(256) void k_mlp(
    const float* __restrict__ agg, const float* __restrict__ b0v,
    const float* __restrict__ W1, const float* __restrict__ b1v,
    const float* __restrict__ W2, const float* __restrict__ b2v,
    float* __restrict__ partials, int rows)
{
    __shared__ float w1s[HH][L1];        // 32 KB
    __shared__ float w2s[L1][L2];        // 8 KB
    __shared__ float hs[32][DD + 8];     // 17.4 KB
    __shared__ float h1s[32][L1 + 4];    // 8.7 KB
    __shared__ float h2s[32][L2 + 4];    // 4.6 KB
    __shared__ float b0s[DD], b1s[L1], b2s[L2];
    __shared__ float oacc[64];

    const int tid = threadIdx.x;
    const int row0 = blockIdx.x * 32;

    for (int u = tid * 4; u < HH * L1; u += 1024)
        *(float4*)(&w1s[u >> 6][u & 63]) = *(const float4*)(W1 + u);
    for (int u = tid * 4; u < L1 * L2; u += 1024)
        *(float4*)(&w2s[u >> 5][u & 31]) = *(const float4*)(W2 + u);
    if (tid < DD) b0s[tid] = b0v[tid];
    if (tid < L1) b1s[tid] = b1v[tid];
    if (tid < L2) b2s[tid] = b2v[tid];
    if (tid < 64) oacc[tid] = 0.f;
    __syncthreads();
    for (int u = tid * 4; u < 32 * DD; u += 1024) {
        const int r = u >> 7, c = u & 127;
        float4 v = make_float4(0.f, 0.f, 0.f, 0.f);
        if (row0 + r < rows) v = *(const float4*)(agg + (size_t)(row0 + r) * DD + c);
        const float4 bb = *(const float4*)(&b0s[c]);
        float a0 = v.x + bb.x, a1 = v.y + bb.y, a2 = v.z + bb.z, a3 = v.w + bb.w;
        float4 g;
        g.x = 0.5f * a0 * (1.f + erff(a0 * 0.70710678118654752f));
        g.y = 0.5f * a1 * (1.f + erff(a1 * 0.70710678118654752f));
        g.z = 0.5f * a2 * (1.f + erff(a2 * 0.70710678118654752f));
        g.w = 0.5f * a3 * (1.f + erff(a3 * 0.70710678118654752f));
        *(float4*)(&hs[r][c]) = g;
    }
    __syncthreads();

    // layer1: thread = 2 rows x 4 cols, single pass over all 128 k
    const int cg = tid & 15;
    const int rg = tid >> 4;
    float4 acc0 = *(const float4*)(&b1s[cg * 4]);
    float4 acc1 = acc0;
    #pragma unroll 4
    for (int j = 0; j < HH; j += 4) {
        float4 wv[4];
        #pragma unroll
        for (int jj = 0; jj < 4; ++jj) wv[jj] = *(const float4*)(&w1s[j + jj][cg * 4]);
        const float4 h0 = *(const float4*)(&hs[rg * 2 + 0][j]);
        const float4 h1 = *(const float4*)(&hs[rg * 2 + 1][j]);
        acc0.x = fmaf(h0.x, wv[0].x, fmaf(h0.y, wv[1].x, fmaf(h0.z, wv[2].x, fmaf(h0.w, wv[3].x, acc0.x))));
        acc0.y = fmaf(h0.x, wv[0].y, fmaf(h0.y, wv[1].y, fmaf(h0.z, wv[2].y, fmaf(h0.w, wv[3].y, acc0.y))));
        acc0.z = fmaf(h0.x, wv[0].z, fmaf(h0.y, wv[1].z, fmaf(h0.z, wv[2].z, fmaf(h0.w, wv[3].z, acc0.z))));
        acc0.w = fmaf(h0.x, wv[0].w, fmaf(h0.y, wv[1].w, fmaf(h0.z, wv[2].w, fmaf(h0.w, wv[3].w, acc0.w))));
        acc1.x = fmaf(h1.x, wv[0].x, fmaf(h1.y, wv[1].x, fmaf(h1.z, wv[2].x, fmaf(h1.w, wv[3].x, acc1.x))));
        acc1.y = fmaf(h1.x, wv[0].y, fmaf(h1.y, wv[1].y, fmaf(h1.z, wv[2].y, fmaf(h1.w, wv[3].y, acc1.y))));
        acc1.z = fmaf(h1.x, wv[0].z, fmaf(h1.y, wv[1].z, fmaf(h1.z, wv[2].z, fmaf(h1.w, wv[3].z, acc1.z))));
        acc1.w = fmaf(h1.x, wv[0].w, fmaf(h1.y, wv[1].w, fmaf(h1.z, wv[2].w, fmaf(h1.w, wv[3].w, acc1.w))));
    }
    acc0.x = fmaxf(acc0.x, 0.f); acc0.y = fmaxf(acc0.y, 0.f);
    acc0.z = fmaxf(acc0.z, 0.f); acc0.w = fmaxf(acc0.w, 0.f);
    acc1.x = fmaxf(acc1.x, 0.f); acc1.y = fmaxf(acc1.y, 0.f);
    acc1.z = fmaxf(acc1.z, 0.f); acc1.w = fmaxf(acc1.w, 0.f);
    *(float4*)(&h1s[rg * 2 + 0][cg * 4]) = acc0;
    *(float4*)(&h1s[rg * 2 + 1][cg * 4]) = acc1;
    __syncthreads();

    // layer2: thread = 1 row x 4 cols
    {
        const int cg2 = tid & 7;
        const int r2 = tid >> 3;
        float4 a = *(const float4*)(&b2s[cg2 * 4]);
        #pragma unroll 4
        for (int j = 0; j < L1; j += 4) {
            float4 wv[4];
            #pragma unroll
            for (int jj = 0; jj < 4; ++jj) wv[jj] = *(const float4*)(&w2s[j + jj][cg2 * 4]);
            const float4 hv = *(const float4*)(&h1s[r2][j]);
            a.x = fmaf(hv.x, wv[0].x, fmaf(hv.y, wv[1].x, fmaf(hv.z, wv[2].x, fmaf(hv.w, wv[3].x, a.x))));
            a.y = fmaf(hv.x, wv[0].y, fmaf(hv.y, wv[1].y, fmaf(hv.z, wv[2].y, fmaf(hv.w, wv[3].y, a.y))));
            a.z = fmaf(hv.x, wv[0].z, fmaf(hv.y, wv[1].z, fmaf(hv.z, wv[2].z, fmaf(hv.w, wv[3].z, a.z))));
            a.w = fmaf(hv.x, wv[0].w, fmaf(hv.y, wv[1].w, fmaf(hv.z, wv[2].w, fmaf(hv.w, wv[3].w, a.w))));
        }
        a.x = fmaxf(a.x, 0.f); a.y = fmaxf(a.y, 0.f);
        a.z = fmaxf(a.z, 0.f); a.w = fmaxf(a.w, 0.f);
        *(float4*)(&h2s[r2][cg2 * 4]) = a;
    }
    __syncthreads();

    // column sums of h2 per batch -> oacc -> partials
    {
        const int c = tid & 31;
        const int g = tid >> 5;
        float p0 = 0.f, p1 = 0.f;
        #pragma unroll
        for (int i = 0; i < 4; ++i) {
            const int r = g * 4 + i;
            const int grow = row0 + r;
            if (grow < rows) {
                const float v = h2s[r][c];
                if (grow >= NN) p1 += v; else p0 += v;
            }
        }
        if (p0 != 0.f) atomicAdd(&oacc[c], p0);
        if (p1 != 0.f) atomicAdd(&oacc[32 + c], p1);
    }
    __syncthreads();
    if (tid < 64) partials[(size_t)blockIdx.x * 64 + tid] = oacc[tid];
}

// ---------------- K4a: parallel reduce of partials into accum[64] ----------------
__global__ __launch_bounds__(256) void k_reduce(
    const float* __restrict__ partials, float* __restrict__ accum, int nblk)
{
    __shared__ float lsum[4][64];
    const int t = threadIdx.x & 63;
    const int w = threadIdx.x >> 6;
    float s = 0.f;
    for (int g = blockIdx.x * 4 + w; g < nblk; g += gridDim.x * 4)
        s += partials[(size_t)g * 64 + t];
    lsum[w][t] = s;
    __syncthreads();
    if (threadIdx.x < 64) {
        const float v = lsum[0][t] + lsum[1][t] + lsum[2][t] + lsum[3][t];
        unsafeAtomicAdd(&accum[t], v);
    }
}

// ---------------- K4b: apply layer3 to mean(h2) ----------------
__global__ __launch_bounds__(64) void k_final(
    const float* __restrict__ accum, const float* __restrict__ W3,
    const float* __restrict__ b3v, float* __restrict__ out)
{
    const int tid = threadIdx.x;
    if (tid < 2 * OO) {
        const int b = tid / OO, o = tid % OO;
        float acc = b3v[o];
        const float inv = 1.0f / (float)NN;
        #pragma unroll
        for (int j = 0; j < L2; ++j) acc += (accum[b * 32 + j] * inv) * W3[j * OO + o];
        out[tid] = acc;
    }
}

extern "C" void kernel_launch(void* const* d_in, const int* in_sizes, int n_in,
                              void* d_out, int out_size, void* d_ws, size_t ws_size,
                              hipStream_t stream) {
    const float* x  = (const float*)d_in[0];
    const int*   ei = (const int*)d_in[1];
    const float* W  = (const float*)d_in[2];
    const float* b0 = (const float*)d_in[3];
    const float* W1 = (const float*)d_in[4];
    const float* b1 = (const float*)d_in[5];
    const float* W2 = (const float*)d_in[6];
    const float* b2 = (const float*)d_in[7];
    const float* W3 = (const float*)d_in[8];
    const float* b3 = (const float*)d_in[9];
    float* out = (float*)d_out;

    const int B = in_sizes[0] / (NN * DD);   // 2
    const int E = in_sizes[1] / 2;           // 800000
    const int rows = B * NN;                 // 100000
    const int nblk_mlp = (rows + 31) / 32;   // 3125
    const int nsb = (NN + 1023) / 1024;      // 49 scan blocks

    // workspace layout (zeroed region contiguous: accum + counts + cursor)
    float* support  = (float*)d_ws;                                  // rows*HH
    float* agg      = support + (size_t)rows * HH;                   // rows*HH
    float* partials = agg + (size_t)rows * HH;                       // nblk_mlp*64
    float* accum    = partials + (size_t)nblk_mlp * 64;              // 64
    int*   counts   = (int*)(accum + 64);                            // NN
    int*   cursor   = counts + NN;                                   // NN
    int*   offsets  = cursor + NN;                                   // NN+1
    int*   blksum   = offsets + NN + 1;                              // 64
    int*   ss       = blksum + 64;                                   // E
    const size_t need = ((size_t)rows * HH * 2 + (size_t)nblk_mlp * 64 + 64) * sizeof(float)
                      + ((size_t)NN * 3 + 1 + 64 + E) * sizeof(int);

    k_support<<<dim3((rows + 63) / 64), dim3(256), 0, stream>>>(x, W, support, rows);

    if (ws_size >= need && nsb <= 64) {
        hipMemsetAsync(accum, 0, (64 + 2 * (size_t)NN) * sizeof(int), stream);
        k_hist<<<dim3((E + 255) / 256), dim3(256), 0, stream>>>(ei, counts, E);
        k_scan1<<<dim3(nsb), dim3(1024), 0, stream>>>(counts, offsets, blksum, NN);
        k_scan2<<<dim3(nsb), dim3(1024), 0, stream>>>(offsets, blksum, nsb, NN);
        k_bucket<<<dim3((E + 255) / 256), dim3(256), 0, stream>>>(ei, offsets, cursor, ss, E);
        k_agg<<<dim3((NN + 3) / 4), dim3(256), 0, stream>>>(
            (const float4*)support, offsets, ss, (float4*)agg, NN);
    } else {
        hipMemsetAsync(accum, 0, 64 * sizeof(float), stream);
        hipMemsetAsync(agg, 0, (size_t)rows * HH * sizeof(float), stream);
        k_scatter<<<dim3((E + 7) / 8), dim3(256), 0, stream>>>(ei, support, agg, E, B);
    }

    k_mlp<<<dim3(nblk_mlp), dim3(256), 0, stream>>>(agg, b0, W1, b1, W2, b2, partials, rows);
    k_reduce<<<dim3(64), dim3(256), 0, stream>>>(partials, accum, nblk_mlp);
    k_final<<<dim3(1), dim3(64), 0, stream>>>(accum, W3, b3, out);
}

// Round 5
// 322.001 us; speedup vs baseline: 9.7019x; 1.2872x over previous
//
#include <hip/hip_runtime.h>
#include <math.h>

#define NN 50000
#define DD 128
#define HH 128
#define L1 64
#define L2 32
#define OO 10

// ---- bf16 helpers (manual: avoid type friction, RNE pack) ----
__device__ __forceinline__ float bf2f_lo(unsigned u) { return __uint_as_float(u << 16); }
__device__ __forceinline__ float bf2f_hi(unsigned u) { return __uint_as_float(u & 0xffff0000u); }
__device__ __forceinline__ unsigned short f2bf(float f) {
    unsigned u = __float_as_uint(f);
    return (unsigned short)((u + 0x7fffu + ((u >> 16) & 1u)) >> 16);
}

// ---------------- K1: support = x @ W (LDS-tiled) + fused dst histogram -------
// 256 threads, 64 rows/block; support stored bf16 (halves gather bytes later).
__global__ __launch_bounds__(256) void k_support(
    const float* __restrict__ x, const float* __restrict__ W,
    unsigned short* __restrict__ supb, int rows,
    const int* __restrict__ ei, int* __restrict__ counts, int E)
{
    __shared__ float xs[64][DD];   // 32 KB
    __shared__ float wh[64][HH];   // 32 KB (one 64-k half of W)
    const int tid = threadIdx.x;
    const int row0 = blockIdx.x * 64;

    for (int u = tid * 4; u < 64 * DD; u += 256 * 4) {
        const int r = u >> 7, c = u & 127;
        float4 v = make_float4(0.f, 0.f, 0.f, 0.f);
        if (row0 + r < rows) v = *(const float4*)(x + (size_t)(row0 + r) * DD + c);
        *(float4*)(&xs[r][c]) = v;
    }

    // fused dst-histogram: independent of the GEMM; atomics fly async under it
    {
        const int chunk = (E + gridDim.x - 1) / gridDim.x;
        const int e0 = blockIdx.x * chunk;
        const int e1 = min(e0 + chunk, E);
        for (int e = e0 + tid; e < e1; e += 256)
            atomicAdd(&counts[ei[(size_t)E + e]], 1);
    }

    const int cg = tid & 31;
    const int rg = tid >> 5;
    float4 acc[8];
    #pragma unroll
    for (int i = 0; i < 8; ++i) acc[i] = make_float4(0.f, 0.f, 0.f, 0.f);

    for (int p = 0; p < 2; ++p) {
        __syncthreads();
        for (int u = tid * 4; u < 64 * HH; u += 256 * 4) {
            const int r = u >> 7, c = u & 127;
            *(float4*)(&wh[r][c]) = *(const float4*)(W + (size_t)(p * 64 + r) * HH + c);
        }
        __syncthreads();
        #pragma unroll 2
        for (int k = 0; k < 64; k += 4) {
            float4 wv[4];
            #pragma unroll
            for (int jj = 0; jj < 4; ++jj) wv[jj] = *(const float4*)(&wh[k + jj][cg * 4]);
            #pragma unroll
            for (int q = 0; q < 2; ++q) {
                #pragma unroll
                for (int i = 0; i < 4; ++i) {
                    const float4 xv = *(const float4*)(&xs[q * 32 + rg * 4 + i][p * 64 + k]);
                    float4* a = &acc[q * 4 + i];
                    a->x = fmaf(xv.x, wv[0].x, fmaf(xv.y, wv[1].x, fmaf(xv.z, wv[2].x, fmaf(xv.w, wv[3].x, a->x))));
                    a->y = fmaf(xv.x, wv[0].y, fmaf(xv.y, wv[1].y, fmaf(xv.z, wv[2].y, fmaf(xv.w, wv[3].y, a->y))));
                    a->z = fmaf(xv.x, wv[0].z, fmaf(xv.y, wv[1].z, fmaf(xv.z, wv[2].z, fmaf(xv.w, wv[3].z, a->z))));
                    a->w = fmaf(xv.x, wv[0].w, fmaf(xv.y, wv[1].w, fmaf(xv.z, wv[2].w, fmaf(xv.w, wv[3].w, a->w))));
                }
            }
        }
    }

    #pragma unroll
    for (int q = 0; q < 2; ++q)
        #pragma unroll
        for (int i = 0; i < 4; ++i) {
            const int r = row0 + q * 32 + rg * 4 + i;
            if (r < rows) {
                const float4 a = acc[q * 4 + i];
                ushort4 o;
                o.x = f2bf(a.x); o.y = f2bf(a.y); o.z = f2bf(a.z); o.w = f2bf(a.w);
                *(ushort4*)(supb + (size_t)r * HH + cg * 4) = o;
            }
        }
}

// ---------------- multi-block scan, stage 1: block-local exclusive scan --------
__global__ __launch_bounds__(1024) void k_scan1(
    const int* __restrict__ counts, int* __restrict__ offsets,
    int* __restrict__ blksum, int n)
{
    __shared__ int wsum[16], woff[16];
    const int tid = threadIdx.x, lane = tid & 63, wv = tid >> 6;
    const int i = blockIdx.x * 1024 + tid;
    int v = (i < n) ? counts[i] : 0;
    int x = v;
    #pragma unroll
    for (int d = 1; d < 64; d <<= 1) { int t = __shfl_up(x, d); if (lane >= d) x += t; }
    if (lane == 63) wsum[wv] = x;
    __syncthreads();
    if (wv == 0 && lane < 16) {
        int y = wsum[lane];
        #pragma unroll
        for (int d = 1; d < 16; d <<= 1) { int t = __shfl_up(y, d); if (lane >= d) y += t; }
        woff[lane] = y - wsum[lane];
        if (lane == 15) blksum[blockIdx.x] = y;
    }
    __syncthreads();
    if (i < n) offsets[i] = woff[wv] + (x - v);
}

// ---------------- multi-block scan, stage 2: add block bases ----------------
__global__ __launch_bounds__(1024) void k_scan2(
    int* __restrict__ offsets, const int* __restrict__ blksum, int nblk, int n)
{
    __shared__ int base_sh, tot_sh;
    const int tid = threadIdx.x, lane = tid & 63, wv = tid >> 6;
    if (wv == 0) {
        int v = (lane < nblk) ? blksum[lane] : 0;
        int x = v;
        #pragma unroll
        for (int d = 1; d < 64; d <<= 1) { int t = __shfl_up(x, d); if (lane >= d) x += t; }
        int incl = __shfl(x, blockIdx.x);
        int own  = __shfl(v, blockIdx.x);
        int tot  = __shfl(x, nblk - 1);
        if (lane == 0) { base_sh = incl - own; tot_sh = tot; }
    }
    __syncthreads();
    const int i = blockIdx.x * 1024 + tid;
    if (i < n) offsets[i] += base_sh;
    if (blockIdx.x == nblk - 1 && tid == 0) offsets[n] = tot_sh;
}

// ---------------- CSR build: bucket src indices by dst ----------------
__global__ __launch_bounds__(256) void k_bucket(
    const int* __restrict__ ei, const int* __restrict__ offsets,
    int* __restrict__ cursor, int* __restrict__ ss, int E)
{
    int e = blockIdx.x * 256 + threadIdx.x;
    if (e < E) {
        int d = ei[E + e];
        int pos = offsets[d] + atomicAdd(&cursor[d], 1);
        ss[pos] = ei[e];
    }
}

// ---------------- K2': bf16 gather-aggregate, x2 unroll, dual accumulators ----
// One wave per dst; lanes 0-31 batch0, 32-63 batch1; 4 bf16 (8 B) per lane.
__global__ __launch_bounds__(256) void k_agg(
    const unsigned short* __restrict__ supb, const int* __restrict__ offsets,
    const int* __restrict__ ss, unsigned short* __restrict__ aggb, int nn)
{
    const int tid = threadIdx.x;
    const int lane = tid & 63;
    const int wv = tid >> 6;
    const int d = blockIdx.x * 4 + wv;
    if (d >= nn) return;
    const int b = lane >> 5;
    const int f = lane & 31;
    const size_t bbase = (size_t)b * nn * HH;
    const unsigned short* sp = supb + bbase + f * 4;
    const int s0 = offsets[d], s1 = offsets[d + 1];
    float4 a = make_float4(0.f, 0.f, 0.f, 0.f);
    float4 a2 = make_float4(0.f, 0.f, 0.f, 0.f);
    int i = s0;
    for (; i + 2 <= s1; i += 2) {
        const int sA = ss[i], sB = ss[i + 1];
        const uint2 rA = *(const uint2*)(sp + (size_t)sA * HH);
        const uint2 rB = *(const uint2*)(sp + (size_t)sB * HH);
        a.x  += bf2f_lo(rA.x); a.y  += bf2f_hi(rA.x); a.z  += bf2f_lo(rA.y); a.w  += bf2f_hi(rA.y);
        a2.x += bf2f_lo(rB.x); a2.y += bf2f_hi(rB.x); a2.z += bf2f_lo(rB.y); a2.w += bf2f_hi(rB.y);
    }
    if (i < s1) {
        const uint2 r = *(const uint2*)(sp + (size_t)ss[i] * HH);
        a.x += bf2f_lo(r.x); a.y += bf2f_hi(r.x); a.z += bf2f_lo(r.y); a.w += bf2f_hi(r.y);
    }
    a.x += a2.x; a.y += a2.y; a.z += a2.z; a.w += a2.w;
    ushort4 o;
    o.x = f2bf(a.x); o.y = f2bf(a.y); o.z = f2bf(a.z); o.w = f2bf(a.w);
    *(ushort4*)(aggb + bbase + (size_t)d * HH + f * 4) = o;
}

// ---------------- Fallback scatter (ws too small for CSR) + convert ----------
__global__ __launch_bounds__(256) void k_scatter(
    const int* __restrict__ ei, const unsigned short* __restrict__ supb,
    float* __restrict__ aggf, int E, int B)
{
    const int tid = threadIdx.x;
    const int eg = tid >> 5;
    const int t4 = (tid & 31) << 2;
    const int e = blockIdx.x * 8 + eg;
    if (e >= E) return;
    const int src = ei[e];
    const int dst = ei[E + e];
    for (int b = 0; b < B; ++b) {
        const uint2 r = *(const uint2*)(supb + ((size_t)b * NN + src) * HH + t4);
        float* ap = aggf + ((size_t)b * NN + dst) * HH + t4;
        unsafeAtomicAdd(ap + 0, bf2f_lo(r.x));
        unsafeAtomicAdd(ap + 1, bf2f_hi(r.x));
        unsafeAtomicAdd(ap + 2, bf2f_lo(r.y));
        unsafeAtomicAdd(ap + 3, bf2f_hi(r.y));
    }
}

__global__ __launch_bounds__(256) void k_cvt(
    const float* __restrict__ in, unsigned short* __restrict__ outb, int n)
{
    int i = blockIdx.x * 256 + threadIdx.x;
    if (i < n) outb[i] = f2bf(in[i]);
}

// ---------------- K3: gelu + MLP(128->64->32) + per-block h2 column sums ------
// 64 rows/block, 512 threads; hs LDS region reused for h1/h2 -> 77 KB, 2 blk/CU.
__global__ __launch_bounds__(512) void k_mlp(
    const unsigned short* __restrict__ aggb, const float* __restrict__ b0v,
    const float* __restrict__ W1, const float* __restrict__ b1v,
    const float* __restrict__ W2, const float* __restrict__ b2v,
    float* __restrict__ partials, int rows)
{
    __shared__ float w1s[HH][L1];        // 32 KB
    __shared__ float w2s[L1][L2];        // 8 KB
    __shared__ float hs[64 * 136];       // 34 KB, reused for h1 (stride 68) & h2 (stride 36)
    __shared__ float b0s[DD], b1s[L1], b2s[L2];
    __shared__ float oacc[64];

    const int tid = threadIdx.x;
    const int row0 = blockIdx.x * 64;

    for (int u = tid * 4; u < HH * L1; u += 2048)
        *(float4*)(&w1s[u >> 6][u & 63]) = *(const float4*)(W1 + u);
    for (int u = tid * 4; u < L1 * L2; u += 2048)
        *(float4*)(&w2s[u >> 5][u & 31]) = *(const float4*)(W2 + u);
    if (tid < DD) b0s[tid] = b0v[tid];
    if (tid < L1) b1s[tid] = b1v[tid];
    if (tid < L2) b2s[tid] = b2v[tid];
    if (tid < 64) oacc[tid] = 0.f;
    __syncthreads();

    // gelu(agg_bf16 + b0) -> hs (8 elems/thread/iter)
    for (int u = tid * 8; u < 64 * DD; u += 512 * 8) {
        const int r = u >> 7, c = u & 127;
        float4 g0 = make_float4(0.f, 0.f, 0.f, 0.f);
        float4 g1 = g0;
        if (row0 + r < rows) {
            const uint4 raw = *(const uint4*)(aggb + (size_t)(row0 + r) * HH + c);
            float v[8];
            v[0] = bf2f_lo(raw.x) + b0s[c + 0]; v[1] = bf2f_hi(raw.x) + b0s[c + 1];
            v[2] = bf2f_lo(raw.y) + b0s[c + 2]; v[3] = bf2f_hi(raw.y) + b0s[c + 3];
            v[4] = bf2f_lo(raw.z) + b0s[c + 4]; v[5] = bf2f_hi(raw.z) + b0s[c + 5];
            v[6] = bf2f_lo(raw.w) + b0s[c + 6]; v[7] = bf2f_hi(raw.w) + b0s[c + 7];
            #pragma unroll
            for (int t = 0; t < 8; ++t) v[t] = 0.5f * v[t] * (1.f + erff(v[t] * 0.70710678118654752f));
            g0 = make_float4(v[0], v[1], v[2], v[3]);
            g1 = make_float4(v[4], v[5], v[6], v[7]);
        }
        *(float4*)(&hs[r * 136 + c]) = g0;
        *(float4*)(&hs[r * 136 + c + 4]) = g1;
    }
    __syncthreads();

    // layer1: thread = 2 rows x 4 cols over 64 rows x 64 cols
    const int cg = tid & 15;
    const int rg = tid >> 4;     // 0..31
    float4 acc0 = *(const float4*)(&b1s[cg * 4]);
    float4 acc1 = acc0;
    #pragma unroll 4
    for (int j = 0; j < HH; j += 4) {
        float4 wv[4];
        #pragma unroll
        for (int jj = 0; jj < 4; ++jj) wv[jj] = *(const float4*)(&w1s[j + jj][cg * 4]);
        const float4 h0 = *(const float4*)(&hs[(rg * 2 + 0) * 136 + j]);
        const float4 h1 = *(const float4*)(&hs[(rg * 2 + 1) * 136 + j]);
        acc0.x = fmaf(h0.x, wv[0].x, fmaf(h0.y, wv[1].x, fmaf(h0.z, wv[2].x, fmaf(h0.w, wv[3].x, acc0.x))));
        acc0.y = fmaf(h0.x, wv[0].y, fmaf(h0.y, wv[1].y, fmaf(h0.z, wv[2].y, fmaf(h0.w, wv[3].y, acc0.y))));
        acc0.z = fmaf(h0.x, wv[0].z, fmaf(h0.y, wv[1].z, fmaf(h0.z, wv[2].z, fmaf(h0.w, wv[3].z, acc0.z))));
        acc0.w = fmaf(h0.x, wv[0].w, fmaf(h0.y, wv[1].w, fmaf(h0.z, wv[2].w, fmaf(h0.w, wv[3].w, acc0.w))));
        acc1.x = fmaf(h1.x, wv[0].x, fmaf(h1.y, wv[1].x, fmaf(h1.z, wv[2].x, fmaf(h1.w, wv[3].x, acc1.x))));
        acc1.y = fmaf(h1.x, wv[0].y, fmaf(h1.y, wv[1].y, fmaf(h1.z, wv[2].y, fmaf(h1.w, wv[3].y, acc1.y))));
        acc1.z = fmaf(h1.x, wv[0].z, fmaf(h1.y, wv[1].z, fmaf(h1.z, wv[2].z, fmaf(h1.w, wv[3].z, acc1.z))));
        acc1.w = fmaf(h1.x, wv[0].w, fmaf(h1.y, wv[1].w, fmaf(h1.z, wv[2].w, fmaf(h1.w, wv[3].w, acc1.w))));
    }
    acc0.x = fmaxf(acc0.x, 0.f); acc0.y = fmaxf(acc0.y, 0.f);
    acc0.z = fmaxf(acc0.z, 0.f); acc0.w = fmaxf(acc0.w, 0.f);
    acc1.x = fmaxf(acc1.x, 0.f); acc1.y = fmaxf(acc1.y, 0.f);
    acc1.z = fmaxf(acc1.z, 0.f); acc1.w = fmaxf(acc1.w, 0.f);
    __syncthreads();                       // hs no longer needed
    float* h1p = hs;                       // [64][68]
    *(float4*)(&h1p[(rg * 2 + 0) * 68 + cg * 4]) = acc0;
    *(float4*)(&h1p[(rg * 2 + 1) * 68 + cg * 4]) = acc1;
    __syncthreads();

    // layer2: thread = 1 row x 4 cols over 64 rows x 32 cols
    float* h2p = hs + 5120;                // [64][36]
    {
        const int cg2 = tid & 7;
        const int r2 = tid >> 3;           // 0..63
        float4 a = *(const float4*)(&b2s[cg2 * 4]);
        #pragma unroll 4
        for (int j = 0; j < L1; j += 4) {
            float4 wv[4];
            #pragma unroll
            for (int jj = 0; jj < 4; ++jj) wv[jj] = *(const float4*)(&w2s[j + jj][cg2 * 4]);
            const float4 hv = *(const float4*)(&h1p[r2 * 68 + j]);
            a.x = fmaf(hv.x, wv[0].x, fmaf(hv.y, wv[1].x, fmaf(hv.z, wv[2].x, fmaf(hv.w, wv[3].x, a.x))));
            a.y = fmaf(hv.x, wv[0].y, fmaf(hv.y, wv[1].y, fmaf(hv.z, wv[2].y, fmaf(hv.w, wv[3].y, a.y))));
            a.z = fmaf(hv.x, wv[0].z, fmaf(hv.y, wv[1].z, fmaf(hv.z, wv[2].z, fmaf(hv.w, wv[3].z, a.z))));
            a.w = fmaf(hv.x, wv[0].w, fmaf(hv.y, wv[1].w, fmaf(hv.z, wv[2].w, fmaf(hv.w, wv[3].w, a.w))));
        }
        a.x = fmaxf(a.x, 0.f); a.y = fmaxf(a.y, 0.f);
        a.z = fmaxf(a.z, 0.f); a.w = fmaxf(a.w, 0.f);
        __syncthreads();                   // h1p no longer needed
        *(float4*)(&h2p[r2 * 36 + cg2 * 4]) = a;
    }
    __syncthreads();

    // column sums of h2 per batch -> oacc -> partials
    {
        const int c = tid & 31;
        const int g = tid >> 5;            // 0..15, 4 rows each
        float p0 = 0.f, p1 = 0.f;
        #pragma unroll
        for (int i = 0; i < 4; ++i) {
            const int r = g * 4 + i;
            const int grow = row0 + r;
            if (grow < rows) {
                const float v = h2p[r * 36 + c];
                if (grow >= NN) p1 += v; else p0 += v;
            }
        }
        if (p0 != 0.f) atomicAdd(&oacc[c], p0);
        if (p1 != 0.f) atomicAdd(&oacc[32 + c], p1);
    }
    __syncthreads();
    if (tid < 64) partials[(size_t)blockIdx.x * 64 + tid] = oacc[tid];
}

// ---------------- K4a: parallel reduce of partials into accum[64] ----------------
__global__ __launch_bounds__(256) void k_reduce(
    const float* __restrict__ partials, float* __restrict__ accum, int nblk)
{
    __shared__ float lsum[4][64];
    const int t = threadIdx.x & 63;
    const int w = threadIdx.x >> 6;
    float s = 0.f;
    for (int g = blockIdx.x * 4 + w; g < nblk; g += gridDim.x * 4)
        s += partials[(size_t)g * 64 + t];
    lsum[w][t] = s;
    __syncthreads();
    if (threadIdx.x < 64) {
        const float v = lsum[0][t] + lsum[1][t] + lsum[2][t] + lsum[3][t];
        unsafeAtomicAdd(&accum[t], v);
    }
}

// ---------------- K4b: apply layer3 to mean(h2) ----------------
__global__ __launch_bounds__(64) void k_final(
    const float* __restrict__ accum, const float* __restrict__ W3,
    const float* __restrict__ b3v, float* __restrict__ out)
{
    const int tid = threadIdx.x;
    if (tid < 2 * OO) {
        const int b = tid / OO, o = tid % OO;
        float acc = b3v[o];
        const float inv = 1.0f / (float)NN;
        #pragma unroll
        for (int j = 0; j < L2; ++j) acc += (accum[b * 32 + j] * inv) * W3[j * OO + o];
        out[tid] = acc;
    }
}

extern "C" void kernel_launch(void* const* d_in, const int* in_sizes, int n_in,
                              void* d_out, int out_size, void* d_ws, size_t ws_size,
                              hipStream_t stream) {
    const float* x  = (const float*)d_in[0];
    const int*   ei = (const int*)d_in[1];
    const float* W  = (const float*)d_in[2];
    const float* b0 = (const float*)d_in[3];
    const float* W1 = (const float*)d_in[4];
    const float* b1 = (const float*)d_in[5];
    const float* W2 = (const float*)d_in[6];
    const float* b2 = (const float*)d_in[7];
    const float* W3 = (const float*)d_in[8];
    const float* b3 = (const float*)d_in[9];
    float* out = (float*)d_out;

    const int B = in_sizes[0] / (NN * DD);   // 2
    const int E = in_sizes[1] / 2;           // 800000
    const int rows = B * NN;                 // 100000
    const int nblk_mlp = (rows + 63) / 64;   // 1563
    const int nsb = (NN + 1023) / 1024;      // 49 scan blocks

    // workspace layout
    unsigned short* supb = (unsigned short*)d_ws;                    // rows*HH bf16
    unsigned short* aggb = supb + (size_t)rows * HH;                 // rows*HH bf16
    float* partials = (float*)(aggb + (size_t)rows * HH);            // nblk_mlp*64
    float* accum    = partials + (size_t)nblk_mlp * 64;              // 64
    int*   counts   = (int*)(accum + 64);                            // NN
    int*   cursor   = counts + NN;                                   // NN
    int*   offsets  = cursor + NN;                                   // NN+1
    int*   blksum   = offsets + NN + 1;                              // 64
    int*   ss       = blksum + 64;                                   // E
    const size_t need = ((size_t)rows * HH * 2) * sizeof(unsigned short)
                      + ((size_t)nblk_mlp * 64 + 64) * sizeof(float)
                      + ((size_t)NN * 3 + 1 + 64 + E) * sizeof(int);

    if (ws_size >= need && nsb <= 64) {
        // zero accum + counts + cursor (contiguous), then CSR-gather path
        hipMemsetAsync(accum, 0, (64 + 2 * (size_t)NN) * sizeof(int), stream);
        k_support<<<dim3(nblk_mlp), dim3(256), 0, stream>>>(x, W, supb, rows, ei, counts, E);
        k_scan1<<<dim3(nsb), dim3(1024), 0, stream>>>(counts, offsets, blksum, NN);
        k_scan2<<<dim3(nsb), dim3(1024), 0, stream>>>(offsets, blksum, nsb, NN);
        k_bucket<<<dim3((E + 255) / 256), dim3(256), 0, stream>>>(ei, offsets, cursor, ss, E);
        k_agg<<<dim3((NN + 3) / 4), dim3(256), 0, stream>>>(supb, offsets, ss, aggb, NN);
    } else {
        // fallback: fp32 atomic scatter into scratch, then convert to bf16
        float* aggf = (float*)counts;  // CSR arrays unused in this path
        hipMemsetAsync(accum, 0, 64 * sizeof(float), stream);
        hipMemsetAsync(aggf, 0, (size_t)rows * HH * sizeof(float), stream);
        k_support<<<dim3(nblk_mlp), dim3(256), 0, stream>>>(x, W, supb, rows, ei, (int*)aggf, 0);
        k_scatter<<<dim3((E + 7) / 8), dim3(256), 0, stream>>>(ei, supb, aggf, E, B);
        k_cvt<<<dim3((rows * HH + 255) / 256), dim3(256), 0, stream>>>(aggf, aggb, rows * HH);
    }

    k_mlp<<<dim3(nblk_mlp), dim3(512), 0, stream>>>(aggb, b0, W1, b1, W2, b2, partials, rows);
    k_reduce<<<dim3(64), dim3(256), 0, stream>>>(partials, accum, nblk_mlp);
    k_final<<<dim3(1), dim3(64), 0, stream>>>(accum, W3, b3, out);
}